// Round 5
// baseline (334.018 us; speedup 1.0000x reference)
//
#include <hip/hip_runtime.h>

// GCN 2-layer, round 5: high-occupancy unified coarse pass, no outdeg kernels.
// r4 profile: k_scatter_coarse 66us (391 blocks -> occ 12%, latency-bound),
// k_outdeg_hist 62us (7 filtered passes, 64KB LDS -> 2 blk/CU). Fix:
//  - CHUNK 8192->2048: 1563 blocks (~6/CU) for hist+scatter.
//  - Out-degree folded into the coarse machinery: dual LDS hist (dst>>7 and
//    src>>7) -> one concatenated scan -> scatter also emits 1-byte (src&127)
//    into src-bucketed sbytes (unique positions, no atomics) -> k_fine_count
//    (128-bin LDS hist per bucket) emits norm_out. outdeg_hist/reduce deleted.
// Aggregation unchanged from r4: bf16 payloads (RNE), f32 accum, transform-
// first: segsum(h[src]) @ W == segsum((h@W)[src]).

#define NN 100000
#define NE 3200000
#define NOUTF 30
#define TPB 256

// coarse bucketing
#define CSHIFT 7
#define CB 128                           // nodes per coarse bucket
#define NB ((NN + CB - 1) / CB)          // 782
#define CHUNK 2048
#define NBLK ((NE + CHUNK - 1) / CHUNK)  // 1563
#define HL (NB * NBLK)                   // 1,222,266
#define HL2 (2 * HL)                     // 2,444,532 (dst half | src half)
#define POOL 8192                        // fine-sort staging (32KB LDS)

// generic scan over HL2
#define GCH 1024
#define NSC2 ((HL2 + GCH - 1) / GCH)     // 2388
#define PIT ((NSC2 + 1023) / 1024)       // 3 items/thread in scan2

__device__ __forceinline__ unsigned short f2bf(float f) {  // round-nearest-even
  unsigned u = __float_as_uint(f);
  u = (u + 0x7FFFu + ((u >> 16) & 1u)) >> 16;
  return (unsigned short)u;
}

// accumulate 8 bf16 (one uint4) into 8 f32
__device__ __forceinline__ void acc8(float* a, const uint4& u) {
  a[0] += __uint_as_float(u.x << 16);
  a[1] += __uint_as_float(u.x & 0xFFFF0000u);
  a[2] += __uint_as_float(u.y << 16);
  a[3] += __uint_as_float(u.y & 0xFFFF0000u);
  a[4] += __uint_as_float(u.z << 16);
  a[5] += __uint_as_float(u.z & 0xFFFF0000u);
  a[6] += __uint_as_float(u.w << 16);
  a[7] += __uint_as_float(u.w & 0xFFFF0000u);
}

// ------ A: dual coarse histogram (dst-buckets and src-buckets, LDS only) ----
__global__ __launch_bounds__(TPB) void k_coarse_hist(const int* __restrict__ src,
                                                     const int* __restrict__ dst,
                                                     int* __restrict__ H) {
  __shared__ int hd[NB], hs[NB];
  int t = threadIdx.x, k = blockIdx.x;
  for (int b = t; b < NB; b += TPB) { hd[b] = 0; hs[b] = 0; }
  __syncthreads();
  int beg = k * CHUNK, end = min(NE, beg + CHUNK);
  for (int i = beg + t; i < end; i += TPB) {
    atomicAdd(&hd[dst[i] >> CSHIFT], 1);
    atomicAdd(&hs[src[i] >> CSHIFT], 1);
  }
  __syncthreads();
  for (int b = t; b < NB; b += TPB) {
    H[b * NBLK + k] = hd[b];
    H[HL + b * NBLK + k] = hs[b];
  }
}

// ------ B: 3-kernel exclusive scan over H[HL2] ------------------------------
__global__ __launch_bounds__(TPB) void g_scan1(const int* __restrict__ a,
                                               int* __restrict__ bsums) {
  int t = threadIdx.x;
  int base = blockIdx.x * GCH + t * 4;
  int s = 0;
#pragma unroll
  for (int j = 0; j < 4; ++j) { int idx = base + j; if (idx < HL2) s += a[idx]; }
  __shared__ int red[TPB];
  red[t] = s; __syncthreads();
  for (int off = TPB / 2; off > 0; off >>= 1) {
    if (t < off) red[t] += red[t + off];
    __syncthreads();
  }
  if (t == 0) bsums[blockIdx.x] = red[0];
}

__global__ __launch_bounds__(1024) void g_scan2(int* __restrict__ bsums) {
  int t = threadIdx.x;
  __shared__ int lds[1024];
  int v[PIT]; int s = 0;
#pragma unroll
  for (int j = 0; j < PIT; ++j) {
    int idx = t * PIT + j;
    v[j] = (idx < NSC2) ? bsums[idx] : 0;
    s += v[j];
  }
  int acc = s; lds[t] = acc; __syncthreads();
  for (int off = 1; off < 1024; off <<= 1) {
    int add = (t >= off) ? lds[t - off] : 0; __syncthreads();
    acc += add; lds[t] = acc; __syncthreads();
  }
  int run = acc - s;  // exclusive base for this thread
#pragma unroll
  for (int j = 0; j < PIT; ++j) {
    int idx = t * PIT + j;
    if (idx < NSC2) bsums[idx] = run;
    run += v[j];
  }
}

__global__ __launch_bounds__(TPB) void g_scan3(int* __restrict__ a,
                                               const int* __restrict__ bsums) {
  int t = threadIdx.x;
  int base = blockIdx.x * GCH + t * 4;
  int v[4]; int s = 0;
#pragma unroll
  for (int j = 0; j < 4; ++j) {
    int idx = base + j;
    v[j] = (idx < HL2) ? a[idx] : 0;
    s += v[j];
  }
  __shared__ int lds[TPB];
  int acc = s; lds[t] = acc; __syncthreads();
  for (int off = 1; off < TPB; off <<= 1) {
    int add = (t >= off) ? lds[t - off] : 0; __syncthreads();
    acc += add; lds[t] = acc; __syncthreads();
  }
  int run = bsums[blockIdx.x] + (acc - s);
#pragma unroll
  for (int j = 0; j < 4; ++j) {
    int idx = base + j;
    if (idx < HL2) a[idx] = run;  // in-place exclusive
    run += v[j];
  }
}

// ------ C: dual coarse scatter via LDS cursors ------------------------------
// dst stream: packed[p] = (src<<7)|(dst&127), p in [0,NE).
// src stream: sbytes[q-NE] = src&127, q in [NE,2NE) (positions unique).
__global__ __launch_bounds__(TPB) void k_scatter_coarse(const int* __restrict__ src,
                                                        const int* __restrict__ dst,
                                                        const int* __restrict__ Hs,
                                                        int* __restrict__ packed,
                                                        unsigned char* __restrict__ sbytes) {
  __shared__ int curD[NB], curS[NB];
  int t = threadIdx.x, k = blockIdx.x;
  for (int b = t; b < NB; b += TPB) {
    curD[b] = Hs[b * NBLK + k];
    curS[b] = Hs[HL + b * NBLK + k];
  }
  __syncthreads();
  int beg = k * CHUNK, end = min(NE, beg + CHUNK);
  for (int i = beg + t; i < end; i += TPB) {
    int s = src[i], d = dst[i];
    int p = atomicAdd(&curD[d >> CSHIFT], 1);
    packed[p] = (s << CSHIFT) | (d & (CB - 1));
    int q = atomicAdd(&curS[s >> CSHIFT], 1);
    sbytes[q - NE] = (unsigned char)(s & (CB - 1));
  }
}

// ------ D: per-bucket fine counting sort (dst) -> src_sorted/row_ptr/norm_in
__global__ __launch_bounds__(TPB) void k_fine_sort(const int* __restrict__ Hs,
                                                   const int* __restrict__ packed,
                                                   int* __restrict__ src_sorted,
                                                   int* __restrict__ row_ptr,
                                                   float* __restrict__ norm_in) {
  __shared__ int hist[CB], scn[CB], cur[CB];
  __shared__ int pool[POOL];
  int t = threadIdx.x, b = blockIdx.x;
  int seg_beg = Hs[b * NBLK];
  int seg_end = (b + 1 < NB) ? Hs[(b + 1) * NBLK] : NE;
  int cnt = seg_end - seg_beg;
  if (t < CB) hist[t] = 0;
  __syncthreads();
  for (int i = seg_beg + t; i < seg_end; i += TPB)
    atomicAdd(&hist[packed[i] & (CB - 1)], 1);
  __syncthreads();
  if (t < CB) scn[t] = hist[t];
  __syncthreads();
  for (int off = 1; off < CB; off <<= 1) {   // Hillis-Steele inclusive
    int add = (t >= off && t < CB) ? scn[t - off] : 0;
    __syncthreads();
    if (t < CB) scn[t] += add;
    __syncthreads();
  }
  if (t < CB) {
    int excl = scn[t] - hist[t];
    cur[t] = excl;
    int node = b * CB + t;
    if (node < NN) {
      row_ptr[node] = seg_beg + excl;
      norm_in[node] = (hist[t] > 0) ? rsqrtf((float)hist[t]) : 0.0f;
    }
  }
  if (b == NB - 1 && t == 0) row_ptr[NN] = NE;
  __syncthreads();
  for (int i = seg_beg + t; i < seg_end; i += TPB) {
    int v = packed[i];
    int p = atomicAdd(&cur[v & (CB - 1)], 1);
    int sv = v >> CSHIFT;
    if (p < POOL) pool[p] = sv;
    else src_sorted[seg_beg + p] = sv;                 // overflow fallback (rare)
  }
  __syncthreads();
  int lim = min(cnt, POOL);
  for (int i = t; i < lim; i += TPB) src_sorted[seg_beg + i] = pool[i];
}

// ------ E: per-bucket fine count (src) -> norm_out --------------------------
__global__ __launch_bounds__(TPB) void k_fine_count(const int* __restrict__ Hs,
                                                    const unsigned char* __restrict__ sbytes,
                                                    float* __restrict__ norm_out) {
  __shared__ int hist[CB];
  int t = threadIdx.x, b = blockIdx.x;
  int seg_beg = Hs[HL + b * NBLK] - NE;
  int seg_end = (b + 1 < NB) ? Hs[HL + (b + 1) * NBLK] - NE : NE;
  if (t < CB) hist[t] = 0;
  __syncthreads();
  for (int i = seg_beg + t; i < seg_end; i += TPB)
    atomicAdd(&hist[sbytes[i]], 1);
  __syncthreads();
  if (t < CB) {
    int node = b * CB + t;
    if (node < NN)
      norm_out[node] = (hist[t] > 0) ? rsqrtf((float)hist[t]) : 0.0f;
  }
}

// ------ GEMM1: xt_b[n] = bf16( norm_out[n] * (x[n] @ W1) )  [64 -> 64] ------
__global__ __launch_bounds__(TPB) void k_gemm1(const float4* __restrict__ x4,
                                               const float* __restrict__ W1,
                                               const float* __restrict__ norm_out,
                                               unsigned short* __restrict__ xt_b) {
  int lane = threadIdx.x & 63;
  int wid = (blockIdx.x * TPB + threadIdx.x) >> 6;
  int nwaves = gridDim.x * (TPB / 64);
  float w[64];
#pragma unroll
  for (int k = 0; k < 64; ++k) w[k] = W1[k * 64 + lane];
  int m = lane >> 4, q = lane & 15;
  for (int grp = wid; grp < NN / 4; grp += nwaves) {
    int nbase = grp * 4;
    float4 rv = x4[(nbase + m) * 16 + q];
    int r0 = __float_as_int(rv.x), r1 = __float_as_int(rv.y);
    int r2 = __float_as_int(rv.z), r3 = __float_as_int(rv.w);
    float acc[4] = {0.f, 0.f, 0.f, 0.f};
#pragma unroll
    for (int mm = 0; mm < 4; ++mm) {
#pragma unroll
      for (int ql = 0; ql < 16; ++ql) {
        int sl = mm * 16 + ql;
        acc[mm] = fmaf(__int_as_float(__builtin_amdgcn_readlane(r0, sl)), w[ql * 4 + 0], acc[mm]);
        acc[mm] = fmaf(__int_as_float(__builtin_amdgcn_readlane(r1, sl)), w[ql * 4 + 1], acc[mm]);
        acc[mm] = fmaf(__int_as_float(__builtin_amdgcn_readlane(r2, sl)), w[ql * 4 + 2], acc[mm]);
        acc[mm] = fmaf(__int_as_float(__builtin_amdgcn_readlane(r3, sl)), w[ql * 4 + 3], acc[mm]);
      }
    }
#pragma unroll
    for (int mm = 0; mm < 4; ++mm) {
      int n = nbase + mm;
      xt_b[n * 64 + lane] = f2bf(norm_out[n] * acc[mm]);  // 128B/row coalesced
    }
  }
}

// -- GEMM2: h1t_b[n][0:32] = bf16( norm_out[n]*(h1[n] @ W2) ), cols 30,31=0 --
__global__ __launch_bounds__(TPB) void k_gemm2(const float4* __restrict__ h1_4,
                                               const float* __restrict__ W2,
                                               const float* __restrict__ norm_out,
                                               unsigned short* __restrict__ h1t_b) {
  int lane = threadIdx.x & 63;
  int wid = (blockIdx.x * TPB + threadIdx.x) >> 6;
  int nwaves = gridDim.x * (TPB / 64);
  int gclamp = (lane < NOUTF) ? lane : 0;
  float w[64];
#pragma unroll
  for (int k = 0; k < 64; ++k) {
    float wv = W2[k * NOUTF + gclamp];
    w[k] = (lane < NOUTF) ? wv : 0.f;
  }
  int m = lane >> 4, q = lane & 15;
  for (int grp = wid; grp < NN / 4; grp += nwaves) {
    int nbase = grp * 4;
    float4 rv = h1_4[(nbase + m) * 16 + q];
    int r0 = __float_as_int(rv.x), r1 = __float_as_int(rv.y);
    int r2 = __float_as_int(rv.z), r3 = __float_as_int(rv.w);
    float acc[4] = {0.f, 0.f, 0.f, 0.f};
#pragma unroll
    for (int mm = 0; mm < 4; ++mm) {
#pragma unroll
      for (int ql = 0; ql < 16; ++ql) {
        int sl = mm * 16 + ql;
        acc[mm] = fmaf(__int_as_float(__builtin_amdgcn_readlane(r0, sl)), w[ql * 4 + 0], acc[mm]);
        acc[mm] = fmaf(__int_as_float(__builtin_amdgcn_readlane(r1, sl)), w[ql * 4 + 1], acc[mm]);
        acc[mm] = fmaf(__int_as_float(__builtin_amdgcn_readlane(r2, sl)), w[ql * 4 + 2], acc[mm]);
        acc[mm] = fmaf(__int_as_float(__builtin_amdgcn_readlane(r3, sl)), w[ql * 4 + 3], acc[mm]);
      }
    }
    if (lane < 32) {
#pragma unroll
      for (int mm = 0; mm < 4; ++mm) {
        int n = nbase + mm;
        unsigned short v = (lane < NOUTF) ? f2bf(norm_out[n] * acc[mm]) : (unsigned short)0;
        h1t_b[n * 32 + lane] = v;  // 64B/row
      }
    }
  }
}

// -- AGG1: h1[n] = relu(norm_in[n]*segsum(xt_b[src]) + b1); bf16 in, f32 out -
__global__ __launch_bounds__(TPB) void k_agg1(const uint4* __restrict__ xt4,
                                              const int* __restrict__ src_sorted,
                                              const int* __restrict__ row_ptr,
                                              const float* __restrict__ norm_in,
                                              const float* __restrict__ b1,
                                              float4* __restrict__ h1_4) {
  int node = (blockIdx.x * TPB + threadIdx.x) >> 6;
  int lane = threadIdx.x & 63;
  int slot = lane >> 3;  // 0..7
  int fl = lane & 7;     // uint4 index within 128B row
  int beg = row_ptr[node];
  int end = row_ptr[node + 1];
  float a[8] = {0.f, 0.f, 0.f, 0.f, 0.f, 0.f, 0.f, 0.f};
  int e = beg + slot;
  for (; e + 8 < end; e += 16) {
    int s0 = src_sorted[e];
    int s1 = src_sorted[e + 8];
    uint4 u0 = xt4[s0 * 8 + fl];
    uint4 u1 = xt4[s1 * 8 + fl];
    acc8(a, u0);
    acc8(a, u1);
  }
  if (e < end) {
    uint4 u0 = xt4[src_sorted[e] * 8 + fl];
    acc8(a, u0);
  }
#pragma unroll
  for (int off = 8; off <= 32; off <<= 1) {
#pragma unroll
    for (int j = 0; j < 8; ++j) a[j] += __shfl_xor(a[j], off);
  }
  if (slot == 0) {
    float ni = norm_in[node];
    float4 blo = reinterpret_cast<const float4*>(b1)[fl * 2];
    float4 bhi = reinterpret_cast<const float4*>(b1)[fl * 2 + 1];
    float4 r0, r1;
    r0.x = fmaxf(fmaf(a[0], ni, blo.x), 0.f);
    r0.y = fmaxf(fmaf(a[1], ni, blo.y), 0.f);
    r0.z = fmaxf(fmaf(a[2], ni, blo.z), 0.f);
    r0.w = fmaxf(fmaf(a[3], ni, blo.w), 0.f);
    r1.x = fmaxf(fmaf(a[4], ni, bhi.x), 0.f);
    r1.y = fmaxf(fmaf(a[5], ni, bhi.y), 0.f);
    r1.z = fmaxf(fmaf(a[6], ni, bhi.z), 0.f);
    r1.w = fmaxf(fmaf(a[7], ni, bhi.w), 0.f);
    h1_4[node * 16 + fl * 2] = r0;
    h1_4[node * 16 + fl * 2 + 1] = r1;
  }
}

// -- AGG2: out[n] = norm_in[n]*segsum(h1t_b[src]) + b2; bf16 in, f32 out -----
__global__ __launch_bounds__(TPB) void k_agg2(const uint4* __restrict__ h1t4,
                                              const int* __restrict__ src_sorted,
                                              const int* __restrict__ row_ptr,
                                              const float* __restrict__ norm_in,
                                              const float* __restrict__ b2,
                                              float* __restrict__ out) {
  int node = (blockIdx.x * TPB + threadIdx.x) >> 6;
  int lane = threadIdx.x & 63;
  int slot = lane >> 2;  // 0..15
  int fl = lane & 3;     // uint4 index within 64B row
  int beg = row_ptr[node];
  int end = row_ptr[node + 1];
  float a[8] = {0.f, 0.f, 0.f, 0.f, 0.f, 0.f, 0.f, 0.f};
  int e = beg + slot;
  for (; e + 16 < end; e += 32) {
    int s0 = src_sorted[e];
    int s1 = src_sorted[e + 16];
    uint4 u0 = h1t4[s0 * 4 + fl];
    uint4 u1 = h1t4[s1 * 4 + fl];
    acc8(a, u0);
    acc8(a, u1);
  }
  if (e < end) {
    uint4 u0 = h1t4[src_sorted[e] * 4 + fl];
    acc8(a, u0);
  }
#pragma unroll
  for (int off = 4; off <= 32; off <<= 1) {
#pragma unroll
    for (int j = 0; j < 8; ++j) a[j] += __shfl_xor(a[j], off);
  }
  if (slot == 0) {
    float ni = norm_in[node];
    int f0 = fl * 8;
    float2* ob = (float2*)(out + (size_t)node * NOUTF);  // rows 120B, 8B-aligned
#pragma unroll
    for (int p = 0; p < 4; ++p) {
      int f = f0 + p * 2;
      if (f < NOUTF) {
        float2 v;
        v.x = fmaf(a[p * 2], ni, b2[f]);
        v.y = fmaf(a[p * 2 + 1], ni, b2[f + 1]);
        ob[f >> 1] = v;
      }
    }
  }
}

extern "C" void kernel_launch(void* const* d_in, const int* in_sizes, int n_in,
                              void* d_out, int out_size, void* d_ws, size_t ws_size,
                              hipStream_t stream) {
  (void)in_sizes; (void)n_in; (void)out_size; (void)ws_size;
  const float* x = (const float*)d_in[0];
  const int* src = (const int*)d_in[1];
  const int* dst = (const int*)d_in[2];
  const float* W1 = (const float*)d_in[3];
  const float* b1 = (const float*)d_in[4];
  const float* W2 = (const float*)d_in[5];
  const float* b2 = (const float*)d_in[6];
  float* out = (float*)d_out;

  // Workspace layout (bytes), total 65,387,904; offsets 16B-aligned.
  // packed (12.8MB) is dead after k_fine_sort -> h1 (25.6MB f32) aliases it.
  // xt_b (12.8MB bf16) dead after agg1 -> h1t_b (6.4MB) aliases it.
  char* ws = (char*)d_ws;
  int* row_ptr = (int*)(ws + 0);                         //    400,128
  float* norm_out = (float*)(ws + 400128);               //    400,000
  float* norm_in = (float*)(ws + 800128);                //    400,000
  int* H = (int*)(ws + 1200128);                         //  9,778,176 (HL2 ints pad)
  int* bsums = (int*)(ws + 10978304);                    //      9,600 (NSC2 ints pad)
  unsigned char* sbytes = (unsigned char*)(ws + 10987904);  // 3,200,000
  int* src_sorted = (int*)(ws + 14187904);               // 12,800,000
  int* packed = (int*)(ws + 26987904);                   // 12,800,000
  float* h1 = (float*)(ws + 26987904);                   // 25,600,000 (aliases packed)
  unsigned short* xt_b = (unsigned short*)(ws + 52587904);  // 12,800,000
  unsigned short* h1t_b = xt_b;                          // reuse (6.4MB)

  k_coarse_hist<<<NBLK, TPB, 0, stream>>>(src, dst, H);
  g_scan1<<<NSC2, TPB, 0, stream>>>(H, bsums);
  g_scan2<<<1, 1024, 0, stream>>>(bsums);
  g_scan3<<<NSC2, TPB, 0, stream>>>(H, bsums);
  k_scatter_coarse<<<NBLK, TPB, 0, stream>>>(src, dst, H, packed, sbytes);
  k_fine_sort<<<NB, TPB, 0, stream>>>(H, packed, src_sorted, row_ptr, norm_in);
  k_fine_count<<<NB, TPB, 0, stream>>>(H, sbytes, norm_out);
  k_gemm1<<<1024, TPB, 0, stream>>>((const float4*)x, W1, norm_out, xt_b);
  k_agg1<<<NN / 4, TPB, 0, stream>>>((const uint4*)xt_b, src_sorted, row_ptr, norm_in, b1, (float4*)h1);
  k_gemm2<<<1024, TPB, 0, stream>>>((const float4*)h1, W2, norm_out, h1t_b);
  k_agg2<<<NN / 4, TPB, 0, stream>>>((const uint4*)h1t_b, src_sorted, row_ptr, norm_in, b2, out);
}

// Round 6
// 294.578 us; speedup vs baseline: 1.1339x; 1.1339x over previous
//
#include <hip/hip_runtime.h>

// GCN 2-layer, round 6: restore scatter write-locality (CHUNK=8192), get
// occupancy from wide blocks (TPB=1024, 16 waves) instead of many blocks.
// r5 lesson: CHUNK=2048 made each (bucket,block) output slice ~10B -> every
// scattered store dirtied a private 64B sector (WRITE_SIZE 200MB, 91us).
// With CHUNK=8192 slices are ~42B (WRITE ~70-90MB); latency hiding now comes
// from 391 blocks x 16 waves ~ 24 waves/CU.
// Structure otherwise = r5: dual coarse hist (dst>>7, src>>7) -> one scan ->
// dual scatter (packed 4B by dst-bucket; sbytes 1B by src-bucket) ->
// fine counting sort (dst) -> row_ptr/norm_in/src_sorted; fine count (src)
// -> norm_out. Aggregation: bf16 payloads (RNE), f32 accum, transform-first
// identity segsum(h[src]) @ W == segsum((h@W)[src]).

#define NN 100000
#define NE 3200000
#define NOUTF 30
#define TPB 256
#define TPBW 1024                        // wide blocks for hist+scatter

// coarse bucketing
#define CSHIFT 7
#define CB 128                           // nodes per coarse bucket
#define NB ((NN + CB - 1) / CB)          // 782
#define CHUNK 8192
#define NBLK ((NE + CHUNK - 1) / CHUNK)  // 391
#define HL (NB * NBLK)                   // 305,762
#define HL2 (2 * HL)                     // 611,524
#define POOL 8192                        // fine-sort staging (32KB LDS)

// generic scan over HL2
#define GCH 1024
#define NSC2 ((HL2 + GCH - 1) / GCH)     // 598
#define PIT ((NSC2 + 1023) / 1024)       // 1

__device__ __forceinline__ unsigned short f2bf(float f) {  // round-nearest-even
  unsigned u = __float_as_uint(f);
  u = (u + 0x7FFFu + ((u >> 16) & 1u)) >> 16;
  return (unsigned short)u;
}

// accumulate 8 bf16 (one uint4) into 8 f32
__device__ __forceinline__ void acc8(float* a, const uint4& u) {
  a[0] += __uint_as_float(u.x << 16);
  a[1] += __uint_as_float(u.x & 0xFFFF0000u);
  a[2] += __uint_as_float(u.y << 16);
  a[3] += __uint_as_float(u.y & 0xFFFF0000u);
  a[4] += __uint_as_float(u.z << 16);
  a[5] += __uint_as_float(u.z & 0xFFFF0000u);
  a[6] += __uint_as_float(u.w << 16);
  a[7] += __uint_as_float(u.w & 0xFFFF0000u);
}

// ------ A: dual coarse histogram (dst-buckets and src-buckets, LDS only) ----
__global__ __launch_bounds__(TPBW) void k_coarse_hist(const int* __restrict__ src,
                                                      const int* __restrict__ dst,
                                                      int* __restrict__ H) {
  __shared__ int hd[NB], hs[NB];
  int t = threadIdx.x, k = blockIdx.x;
  for (int b = t; b < NB; b += TPBW) { hd[b] = 0; hs[b] = 0; }
  __syncthreads();
  int beg = k * CHUNK, end = min(NE, beg + CHUNK);
  for (int i = beg + t; i < end; i += TPBW) {
    atomicAdd(&hd[dst[i] >> CSHIFT], 1);
    atomicAdd(&hs[src[i] >> CSHIFT], 1);
  }
  __syncthreads();
  for (int b = t; b < NB; b += TPBW) {
    H[b * NBLK + k] = hd[b];
    H[HL + b * NBLK + k] = hs[b];
  }
}

// ------ B: 3-kernel exclusive scan over H[HL2] ------------------------------
__global__ __launch_bounds__(TPB) void g_scan1(const int* __restrict__ a,
                                               int* __restrict__ bsums) {
  int t = threadIdx.x;
  int base = blockIdx.x * GCH + t * 4;
  int s = 0;
#pragma unroll
  for (int j = 0; j < 4; ++j) { int idx = base + j; if (idx < HL2) s += a[idx]; }
  __shared__ int red[TPB];
  red[t] = s; __syncthreads();
  for (int off = TPB / 2; off > 0; off >>= 1) {
    if (t < off) red[t] += red[t + off];
    __syncthreads();
  }
  if (t == 0) bsums[blockIdx.x] = red[0];
}

__global__ __launch_bounds__(1024) void g_scan2(int* __restrict__ bsums) {
  int t = threadIdx.x;
  __shared__ int lds[1024];
  int v[PIT]; int s = 0;
#pragma unroll
  for (int j = 0; j < PIT; ++j) {
    int idx = t * PIT + j;
    v[j] = (idx < NSC2) ? bsums[idx] : 0;
    s += v[j];
  }
  int acc = s; lds[t] = acc; __syncthreads();
  for (int off = 1; off < 1024; off <<= 1) {
    int add = (t >= off) ? lds[t - off] : 0; __syncthreads();
    acc += add; lds[t] = acc; __syncthreads();
  }
  int run = acc - s;  // exclusive base for this thread
#pragma unroll
  for (int j = 0; j < PIT; ++j) {
    int idx = t * PIT + j;
    if (idx < NSC2) bsums[idx] = run;
    run += v[j];
  }
}

__global__ __launch_bounds__(TPB) void g_scan3(int* __restrict__ a,
                                               const int* __restrict__ bsums) {
  int t = threadIdx.x;
  int base = blockIdx.x * GCH + t * 4;
  int v[4]; int s = 0;
#pragma unroll
  for (int j = 0; j < 4; ++j) {
    int idx = base + j;
    v[j] = (idx < HL2) ? a[idx] : 0;
    s += v[j];
  }
  __shared__ int lds[TPB];
  int acc = s; lds[t] = acc; __syncthreads();
  for (int off = 1; off < TPB; off <<= 1) {
    int add = (t >= off) ? lds[t - off] : 0; __syncthreads();
    acc += add; lds[t] = acc; __syncthreads();
  }
  int run = bsums[blockIdx.x] + (acc - s);
#pragma unroll
  for (int j = 0; j < 4; ++j) {
    int idx = base + j;
    if (idx < HL2) a[idx] = run;  // in-place exclusive
    run += v[j];
  }
}

// ------ C: dual coarse scatter via LDS cursors (wide blocks) ----------------
// dst stream: packed[p] = (src<<7)|(dst&127), p in [0,NE).
// src stream: sbytes[q-NE] = src&127, q in [NE,2NE) (positions unique).
__global__ __launch_bounds__(TPBW) void k_scatter_coarse(const int* __restrict__ src,
                                                         const int* __restrict__ dst,
                                                         const int* __restrict__ Hs,
                                                         int* __restrict__ packed,
                                                         unsigned char* __restrict__ sbytes) {
  __shared__ int curD[NB], curS[NB];
  int t = threadIdx.x, k = blockIdx.x;
  for (int b = t; b < NB; b += TPBW) {
    curD[b] = Hs[b * NBLK + k];
    curS[b] = Hs[HL + b * NBLK + k];
  }
  __syncthreads();
  int beg = k * CHUNK, end = min(NE, beg + CHUNK);
  for (int i = beg + t; i < end; i += TPBW) {
    int s = src[i], d = dst[i];
    int p = atomicAdd(&curD[d >> CSHIFT], 1);
    packed[p] = (s << CSHIFT) | (d & (CB - 1));
    int q = atomicAdd(&curS[s >> CSHIFT], 1);
    sbytes[q - NE] = (unsigned char)(s & (CB - 1));
  }
}

// ------ D: per-bucket fine counting sort (dst) -> src_sorted/row_ptr/norm_in
__global__ __launch_bounds__(TPB) void k_fine_sort(const int* __restrict__ Hs,
                                                   const int* __restrict__ packed,
                                                   int* __restrict__ src_sorted,
                                                   int* __restrict__ row_ptr,
                                                   float* __restrict__ norm_in) {
  __shared__ int hist[CB], scn[CB], cur[CB];
  __shared__ int pool[POOL];
  int t = threadIdx.x, b = blockIdx.x;
  int seg_beg = Hs[b * NBLK];
  int seg_end = (b + 1 < NB) ? Hs[(b + 1) * NBLK] : NE;
  int cnt = seg_end - seg_beg;
  if (t < CB) hist[t] = 0;
  __syncthreads();
  for (int i = seg_beg + t; i < seg_end; i += TPB)
    atomicAdd(&hist[packed[i] & (CB - 1)], 1);
  __syncthreads();
  if (t < CB) scn[t] = hist[t];
  __syncthreads();
  for (int off = 1; off < CB; off <<= 1) {   // Hillis-Steele inclusive
    int add = (t >= off && t < CB) ? scn[t - off] : 0;
    __syncthreads();
    if (t < CB) scn[t] += add;
    __syncthreads();
  }
  if (t < CB) {
    int excl = scn[t] - hist[t];
    cur[t] = excl;
    int node = b * CB + t;
    if (node < NN) {
      row_ptr[node] = seg_beg + excl;
      norm_in[node] = (hist[t] > 0) ? rsqrtf((float)hist[t]) : 0.0f;
    }
  }
  if (b == NB - 1 && t == 0) row_ptr[NN] = NE;
  __syncthreads();
  for (int i = seg_beg + t; i < seg_end; i += TPB) {
    int v = packed[i];
    int p = atomicAdd(&cur[v & (CB - 1)], 1);
    int sv = v >> CSHIFT;
    if (p < POOL) pool[p] = sv;
    else src_sorted[seg_beg + p] = sv;                 // overflow fallback (rare)
  }
  __syncthreads();
  int lim = min(cnt, POOL);
  for (int i = t; i < lim; i += TPB) src_sorted[seg_beg + i] = pool[i];
}

// ------ E: per-bucket fine count (src) -> norm_out --------------------------
__global__ __launch_bounds__(TPB) void k_fine_count(const int* __restrict__ Hs,
                                                    const unsigned char* __restrict__ sbytes,
                                                    float* __restrict__ norm_out) {
  __shared__ int hist[CB];
  int t = threadIdx.x, b = blockIdx.x;
  int seg_beg = Hs[HL + b * NBLK] - NE;
  int seg_end = (b + 1 < NB) ? Hs[HL + (b + 1) * NBLK] - NE : NE;
  if (t < CB) hist[t] = 0;
  __syncthreads();
  for (int i = seg_beg + t; i < seg_end; i += TPB)
    atomicAdd(&hist[sbytes[i]], 1);
  __syncthreads();
  if (t < CB) {
    int node = b * CB + t;
    if (node < NN)
      norm_out[node] = (hist[t] > 0) ? rsqrtf((float)hist[t]) : 0.0f;
  }
}

// ------ GEMM1: xt_b[n] = bf16( norm_out[n] * (x[n] @ W1) )  [64 -> 64] ------
__global__ __launch_bounds__(TPB) void k_gemm1(const float4* __restrict__ x4,
                                               const float* __restrict__ W1,
                                               const float* __restrict__ norm_out,
                                               unsigned short* __restrict__ xt_b) {
  int lane = threadIdx.x & 63;
  int wid = (blockIdx.x * TPB + threadIdx.x) >> 6;
  int nwaves = gridDim.x * (TPB / 64);
  float w[64];
#pragma unroll
  for (int k = 0; k < 64; ++k) w[k] = W1[k * 64 + lane];
  int m = lane >> 4, q = lane & 15;
  for (int grp = wid; grp < NN / 4; grp += nwaves) {
    int nbase = grp * 4;
    float4 rv = x4[(nbase + m) * 16 + q];
    int r0 = __float_as_int(rv.x), r1 = __float_as_int(rv.y);
    int r2 = __float_as_int(rv.z), r3 = __float_as_int(rv.w);
    float acc[4] = {0.f, 0.f, 0.f, 0.f};
#pragma unroll
    for (int mm = 0; mm < 4; ++mm) {
#pragma unroll
      for (int ql = 0; ql < 16; ++ql) {
        int sl = mm * 16 + ql;
        acc[mm] = fmaf(__int_as_float(__builtin_amdgcn_readlane(r0, sl)), w[ql * 4 + 0], acc[mm]);
        acc[mm] = fmaf(__int_as_float(__builtin_amdgcn_readlane(r1, sl)), w[ql * 4 + 1], acc[mm]);
        acc[mm] = fmaf(__int_as_float(__builtin_amdgcn_readlane(r2, sl)), w[ql * 4 + 2], acc[mm]);
        acc[mm] = fmaf(__int_as_float(__builtin_amdgcn_readlane(r3, sl)), w[ql * 4 + 3], acc[mm]);
      }
    }
#pragma unroll
    for (int mm = 0; mm < 4; ++mm) {
      int n = nbase + mm;
      xt_b[n * 64 + lane] = f2bf(norm_out[n] * acc[mm]);  // 128B/row coalesced
    }
  }
}

// -- GEMM2: h1t_b[n][0:32] = bf16( norm_out[n]*(h1[n] @ W2) ), cols 30,31=0 --
__global__ __launch_bounds__(TPB) void k_gemm2(const float4* __restrict__ h1_4,
                                               const float* __restrict__ W2,
                                               const float* __restrict__ norm_out,
                                               unsigned short* __restrict__ h1t_b) {
  int lane = threadIdx.x & 63;
  int wid = (blockIdx.x * TPB + threadIdx.x) >> 6;
  int nwaves = gridDim.x * (TPB / 64);
  int gclamp = (lane < NOUTF) ? lane : 0;
  float w[64];
#pragma unroll
  for (int k = 0; k < 64; ++k) {
    float wv = W2[k * NOUTF + gclamp];
    w[k] = (lane < NOUTF) ? wv : 0.f;
  }
  int m = lane >> 4, q = lane & 15;
  for (int grp = wid; grp < NN / 4; grp += nwaves) {
    int nbase = grp * 4;
    float4 rv = h1_4[(nbase + m) * 16 + q];
    int r0 = __float_as_int(rv.x), r1 = __float_as_int(rv.y);
    int r2 = __float_as_int(rv.z), r3 = __float_as_int(rv.w);
    float acc[4] = {0.f, 0.f, 0.f, 0.f};
#pragma unroll
    for (int mm = 0; mm < 4; ++mm) {
#pragma unroll
      for (int ql = 0; ql < 16; ++ql) {
        int sl = mm * 16 + ql;
        acc[mm] = fmaf(__int_as_float(__builtin_amdgcn_readlane(r0, sl)), w[ql * 4 + 0], acc[mm]);
        acc[mm] = fmaf(__int_as_float(__builtin_amdgcn_readlane(r1, sl)), w[ql * 4 + 1], acc[mm]);
        acc[mm] = fmaf(__int_as_float(__builtin_amdgcn_readlane(r2, sl)), w[ql * 4 + 2], acc[mm]);
        acc[mm] = fmaf(__int_as_float(__builtin_amdgcn_readlane(r3, sl)), w[ql * 4 + 3], acc[mm]);
      }
    }
    if (lane < 32) {
#pragma unroll
      for (int mm = 0; mm < 4; ++mm) {
        int n = nbase + mm;
        unsigned short v = (lane < NOUTF) ? f2bf(norm_out[n] * acc[mm]) : (unsigned short)0;
        h1t_b[n * 32 + lane] = v;  // 64B/row
      }
    }
  }
}

// -- AGG1: h1[n] = relu(norm_in[n]*segsum(xt_b[src]) + b1); bf16 in, f32 out -
__global__ __launch_bounds__(TPB) void k_agg1(const uint4* __restrict__ xt4,
                                              const int* __restrict__ src_sorted,
                                              const int* __restrict__ row_ptr,
                                              const float* __restrict__ norm_in,
                                              const float* __restrict__ b1,
                                              float4* __restrict__ h1_4) {
  int node = (blockIdx.x * TPB + threadIdx.x) >> 6;
  int lane = threadIdx.x & 63;
  int slot = lane >> 3;  // 0..7
  int fl = lane & 7;     // uint4 index within 128B row
  int beg = row_ptr[node];
  int end = row_ptr[node + 1];
  float a[8] = {0.f, 0.f, 0.f, 0.f, 0.f, 0.f, 0.f, 0.f};
  int e = beg + slot;
  for (; e + 8 < end; e += 16) {
    int s0 = src_sorted[e];
    int s1 = src_sorted[e + 8];
    uint4 u0 = xt4[s0 * 8 + fl];
    uint4 u1 = xt4[s1 * 8 + fl];
    acc8(a, u0);
    acc8(a, u1);
  }
  if (e < end) {
    uint4 u0 = xt4[src_sorted[e] * 8 + fl];
    acc8(a, u0);
  }
#pragma unroll
  for (int off = 8; off <= 32; off <<= 1) {
#pragma unroll
    for (int j = 0; j < 8; ++j) a[j] += __shfl_xor(a[j], off);
  }
  if (slot == 0) {
    float ni = norm_in[node];
    float4 blo = reinterpret_cast<const float4*>(b1)[fl * 2];
    float4 bhi = reinterpret_cast<const float4*>(b1)[fl * 2 + 1];
    float4 r0, r1;
    r0.x = fmaxf(fmaf(a[0], ni, blo.x), 0.f);
    r0.y = fmaxf(fmaf(a[1], ni, blo.y), 0.f);
    r0.z = fmaxf(fmaf(a[2], ni, blo.z), 0.f);
    r0.w = fmaxf(fmaf(a[3], ni, blo.w), 0.f);
    r1.x = fmaxf(fmaf(a[4], ni, bhi.x), 0.f);
    r1.y = fmaxf(fmaf(a[5], ni, bhi.y), 0.f);
    r1.z = fmaxf(fmaf(a[6], ni, bhi.z), 0.f);
    r1.w = fmaxf(fmaf(a[7], ni, bhi.w), 0.f);
    h1_4[node * 16 + fl * 2] = r0;
    h1_4[node * 16 + fl * 2 + 1] = r1;
  }
}

// -- AGG2: out[n] = norm_in[n]*segsum(h1t_b[src]) + b2; bf16 in, f32 out -----
__global__ __launch_bounds__(TPB) void k_agg2(const uint4* __restrict__ h1t4,
                                              const int* __restrict__ src_sorted,
                                              const int* __restrict__ row_ptr,
                                              const float* __restrict__ norm_in,
                                              const float* __restrict__ b2,
                                              float* __restrict__ out) {
  int node = (blockIdx.x * TPB + threadIdx.x) >> 6;
  int lane = threadIdx.x & 63;
  int slot = lane >> 2;  // 0..15
  int fl = lane & 3;     // uint4 index within 64B row
  int beg = row_ptr[node];
  int end = row_ptr[node + 1];
  float a[8] = {0.f, 0.f, 0.f, 0.f, 0.f, 0.f, 0.f, 0.f};
  int e = beg + slot;
  for (; e + 16 < end; e += 32) {
    int s0 = src_sorted[e];
    int s1 = src_sorted[e + 16];
    uint4 u0 = h1t4[s0 * 4 + fl];
    uint4 u1 = h1t4[s1 * 4 + fl];
    acc8(a, u0);
    acc8(a, u1);
  }
  if (e < end) {
    uint4 u0 = h1t4[src_sorted[e] * 4 + fl];
    acc8(a, u0);
  }
#pragma unroll
  for (int off = 4; off <= 32; off <<= 1) {
#pragma unroll
    for (int j = 0; j < 8; ++j) a[j] += __shfl_xor(a[j], off);
  }
  if (slot == 0) {
    float ni = norm_in[node];
    int f0 = fl * 8;
    float2* ob = (float2*)(out + (size_t)node * NOUTF);  // rows 120B, 8B-aligned
#pragma unroll
    for (int p = 0; p < 4; ++p) {
      int f = f0 + p * 2;
      if (f < NOUTF) {
        float2 v;
        v.x = fmaf(a[p * 2], ni, b2[f]);
        v.y = fmaf(a[p * 2 + 1], ni, b2[f + 1]);
        ob[f >> 1] = v;
      }
    }
  }
}

extern "C" void kernel_launch(void* const* d_in, const int* in_sizes, int n_in,
                              void* d_out, int out_size, void* d_ws, size_t ws_size,
                              hipStream_t stream) {
  (void)in_sizes; (void)n_in; (void)out_size; (void)ws_size;
  const float* x = (const float*)d_in[0];
  const int* src = (const int*)d_in[1];
  const int* dst = (const int*)d_in[2];
  const float* W1 = (const float*)d_in[3];
  const float* b1 = (const float*)d_in[4];
  const float* W2 = (const float*)d_in[5];
  const float* b2 = (const float*)d_in[6];
  float* out = (float*)d_out;

  // Workspace layout (bytes); offsets 16B-aligned.
  // packed (12.8MB) dead after k_fine_sort -> h1 (25.6MB f32) aliases it.
  // xt_b (12.8MB bf16) dead after agg1 -> h1t_b (6.4MB) aliases it.
  char* ws = (char*)d_ws;
  int* row_ptr = (int*)(ws + 0);                         //    400,128
  float* norm_out = (float*)(ws + 400128);               //    400,000
  float* norm_in = (float*)(ws + 800128);                //    400,000
  int* H = (int*)(ws + 1200128);                         //  2,446,208 (HL2 ints pad)
  int* bsums = (int*)(ws + 3646336);                     //      2,432 (NSC2 ints pad)
  unsigned char* sbytes = (unsigned char*)(ws + 3648768);   // 3,200,000
  int* src_sorted = (int*)(ws + 6848768);                // 12,800,000
  int* packed = (int*)(ws + 19648768);                   // 12,800,000
  float* h1 = (float*)(ws + 19648768);                   // 25,600,000 (aliases packed)
  unsigned short* xt_b = (unsigned short*)(ws + 45248768);  // 12,800,000
  unsigned short* h1t_b = xt_b;                          // reuse (6.4MB)

  k_coarse_hist<<<NBLK, TPBW, 0, stream>>>(src, dst, H);
  g_scan1<<<NSC2, TPB, 0, stream>>>(H, bsums);
  g_scan2<<<1, 1024, 0, stream>>>(bsums);
  g_scan3<<<NSC2, TPB, 0, stream>>>(H, bsums);
  k_scatter_coarse<<<NBLK, TPBW, 0, stream>>>(src, dst, H, packed, sbytes);
  k_fine_sort<<<NB, TPB, 0, stream>>>(H, packed, src_sorted, row_ptr, norm_in);
  k_fine_count<<<NB, TPB, 0, stream>>>(H, sbytes, norm_out);
  k_gemm1<<<1024, TPB, 0, stream>>>((const float4*)x, W1, norm_out, xt_b);
  k_agg1<<<NN / 4, TPB, 0, stream>>>((const uint4*)xt_b, src_sorted, row_ptr, norm_in, b1, (float4*)h1);
  k_gemm2<<<1024, TPB, 0, stream>>>((const float4*)h1, W2, norm_out, h1t_b);
  k_agg2<<<NN / 4, TPB, 0, stream>>>((const uint4*)h1t_b, src_sorted, row_ptr, norm_in, b2, out);
}

// Round 7
// 290.129 us; speedup vs baseline: 1.1513x; 1.0153x over previous
//
#include <hip/hip_runtime.h>

// GCN 2-layer, round 7: LDS-staged scatter with burst flush.
// r6 lesson: cursor-sliced scatter writes (21-int slices, 16 interleaved
// waves) dirty partial 64B sectors -> 9x write amp (145MB for 16MB payload).
// Fix: each block sorts its CHUNK inside LDS (block-local hist + scan +
// LDS scatter), then flushes each bucket's run as ONE contiguous coalesced
// burst into its scanned global slice. Plus: dst buckets CB=256 (84B slices),
// src stream at CB_S=1024 with 2-byte payload (167B slices), bijective XCD
// swizzle so adjacent slices are written by the same XCD's L2.
// Pipeline: k_hist (dual LDS hist) -> 3-kernel scan over H ->
// k_scatter (reg-stage, LDS sort, burst flush) ->
// k_fine_sort (256-bin counting sort -> src_sorted/row_ptr/norm_in) ->
// k_fine_count (1024-bin hist -> norm_out) ->
// GEMM1 -> AGG1 -> GEMM2 -> AGG2 (bf16 payloads, f32 accum, transform-first:
// segsum(h[src]) @ W == segsum((h@W)[src]) ).

#define NN 100000
#define NE 3200000
#define NOUTF 30
#define TPB 256
#define TPBW 1024                          // hist blocks
#define TPBS 512                           // scatter blocks

// dst stream buckets
#define DSH 8
#define DCB 256
#define DNB ((NN + DCB - 1) / DCB)         // 391
// src stream buckets
#define SSH 10
#define SCB 1024
#define SNB ((NN + SCB - 1) / SCB)         // 98

#define CHUNK 8192
#define NBLK ((NE + CHUNK - 1) / CHUNK)    // 391
#define HLD (DNB * NBLK)                   // 152,881
#define HLS (SNB * NBLK)                   // 38,318
#define HLT (HLD + HLS)                    // 191,199
#define EPT (CHUNK / TPBS)                 // 16 edges per scatter thread

#define GCH 1024
#define NSC ((HLT + GCH - 1) / GCH)        // 187

#define POOL 9216                          // fine-sort staging (36KB LDS)

__device__ __forceinline__ unsigned short f2bf(float f) {  // round-nearest-even
  unsigned u = __float_as_uint(f);
  u = (u + 0x7FFFu + ((u >> 16) & 1u)) >> 16;
  return (unsigned short)u;
}

// accumulate 8 bf16 (one uint4) into 8 f32
__device__ __forceinline__ void acc8(float* a, const uint4& u) {
  a[0] += __uint_as_float(u.x << 16);
  a[1] += __uint_as_float(u.x & 0xFFFF0000u);
  a[2] += __uint_as_float(u.y << 16);
  a[3] += __uint_as_float(u.y & 0xFFFF0000u);
  a[4] += __uint_as_float(u.z << 16);
  a[5] += __uint_as_float(u.z & 0xFFFF0000u);
  a[6] += __uint_as_float(u.w << 16);
  a[7] += __uint_as_float(u.w & 0xFFFF0000u);
}

// bijective XCD swizzle (m204 variant): consecutive swizzled ids -> same XCD
__device__ __forceinline__ int xcd_swz(int orig, int n) {
  int q = n / 8, r = n % 8;
  int xcd = orig % 8, idx = orig / 8;
  return (xcd < r ? xcd * (q + 1) : r * (q + 1) + (xcd - r) * q) + idx;
}

// ------ A: dual coarse histogram (dst>>8 and src>>10, LDS only) -------------
__global__ __launch_bounds__(TPBW) void k_hist(const int* __restrict__ src,
                                               const int* __restrict__ dst,
                                               int* __restrict__ H) {
  __shared__ int hd[DNB], hs[SNB];
  int t = threadIdx.x, k = blockIdx.x;
  for (int b = t; b < DNB; b += TPBW) hd[b] = 0;
  for (int b = t; b < SNB; b += TPBW) hs[b] = 0;
  __syncthreads();
  int beg = k * CHUNK, end = min(NE, beg + CHUNK);
  for (int i = beg + t; i < end; i += TPBW) {
    atomicAdd(&hd[dst[i] >> DSH], 1);
    atomicAdd(&hs[src[i] >> SSH], 1);
  }
  __syncthreads();
  for (int b = t; b < DNB; b += TPBW) H[b * NBLK + k] = hd[b];
  for (int b = t; b < SNB; b += TPBW) H[HLD + b * NBLK + k] = hs[b];
}

// ------ B: 3-kernel exclusive scan over H[HLT] -------------------------------
__global__ __launch_bounds__(TPB) void g_scan1(const int* __restrict__ a,
                                               int* __restrict__ bsums) {
  int t = threadIdx.x;
  int base = blockIdx.x * GCH + t * 4;
  int s = 0;
#pragma unroll
  for (int j = 0; j < 4; ++j) { int idx = base + j; if (idx < HLT) s += a[idx]; }
  __shared__ int red[TPB];
  red[t] = s; __syncthreads();
  for (int off = TPB / 2; off > 0; off >>= 1) {
    if (t < off) red[t] += red[t + off];
    __syncthreads();
  }
  if (t == 0) bsums[blockIdx.x] = red[0];
}

__global__ __launch_bounds__(1024) void g_scan2(int* __restrict__ bsums) {
  int t = threadIdx.x;
  __shared__ int lds[1024];
  int v = (t < NSC) ? bsums[t] : 0;
  int acc = v; lds[t] = acc; __syncthreads();
  for (int off = 1; off < 1024; off <<= 1) {
    int add = (t >= off) ? lds[t - off] : 0; __syncthreads();
    acc += add; lds[t] = acc; __syncthreads();
  }
  if (t < NSC) bsums[t] = acc - v;  // exclusive
}

__global__ __launch_bounds__(TPB) void g_scan3(int* __restrict__ a,
                                               const int* __restrict__ bsums) {
  int t = threadIdx.x;
  int base = blockIdx.x * GCH + t * 4;
  int v[4]; int s = 0;
#pragma unroll
  for (int j = 0; j < 4; ++j) {
    int idx = base + j;
    v[j] = (idx < HLT) ? a[idx] : 0;
    s += v[j];
  }
  __shared__ int lds[TPB];
  int acc = s; lds[t] = acc; __syncthreads();
  for (int off = 1; off < TPB; off <<= 1) {
    int add = (t >= off) ? lds[t - off] : 0; __syncthreads();
    acc += add; lds[t] = acc; __syncthreads();
  }
  int run = bsums[blockIdx.x] + (acc - s);
#pragma unroll
  for (int j = 0; j < 4; ++j) {
    int idx = base + j;
    if (idx < HLT) a[idx] = run;  // in-place exclusive
    run += v[j];
  }
}

// ------ C: LDS-staged dual scatter with contiguous burst flush --------------
__global__ __launch_bounds__(TPBS) void k_scatter(const int* __restrict__ src,
                                                  const int* __restrict__ dst,
                                                  const int* __restrict__ Hsc,
                                                  int* __restrict__ packed,
                                                  unsigned short* __restrict__ ss) {
  __shared__ int pack_lds[CHUNK];            // 32KB
  __shared__ unsigned short ss_lds[CHUNK];   // 16KB
  __shared__ int baseD[DNB + 1], curD[DNB];
  __shared__ int baseS[SNB + 1], curS[SNB];
  __shared__ int scanbuf[TPBS];
  int t = threadIdx.x;
  int k = xcd_swz((int)blockIdx.x, NBLK);    // adjacent chunks -> same XCD
  int beg = k * CHUNK, end = min(NE, beg + CHUNK);
  int cnt = end - beg;

  // register-stage this chunk's edges (coalesced reads, read once)
  int es[EPT], ed[EPT];
#pragma unroll
  for (int j = 0; j < EPT; ++j) {
    int i = beg + j * TPBS + t;
    if (i < end) { es[j] = src[i]; ed[j] = dst[i]; }
    else { es[j] = -1; ed[j] = -1; }
  }

  // block-local histograms (curD/curS double as hist accumulators)
  for (int b = t; b < DNB; b += TPBS) curD[b] = 0;
  for (int b = t; b < SNB; b += TPBS) curS[b] = 0;
  __syncthreads();
#pragma unroll
  for (int j = 0; j < EPT; ++j) {
    if (ed[j] >= 0) {
      atomicAdd(&curD[ed[j] >> DSH], 1);
      atomicAdd(&curS[es[j] >> SSH], 1);
    }
  }
  __syncthreads();

  // exclusive scan of curD -> baseD (DNB=391 <= TPBS)
  {
    int v = (t < DNB) ? curD[t] : 0;
    int acc = v; scanbuf[t] = acc; __syncthreads();
    for (int off = 1; off < TPBS; off <<= 1) {
      int add = (t >= off) ? scanbuf[t - off] : 0; __syncthreads();
      acc += add; scanbuf[t] = acc; __syncthreads();
    }
    if (t < DNB) baseD[t] = acc - v;
    if (t == 0) baseD[DNB] = cnt;
  }
  __syncthreads();
  // exclusive scan of curS -> baseS (SNB=98)
  {
    int v = (t < SNB) ? curS[t] : 0;
    int acc = v; scanbuf[t] = acc; __syncthreads();
    for (int off = 1; off < TPBS; off <<= 1) {
      int add = (t >= off) ? scanbuf[t - off] : 0; __syncthreads();
      acc += add; scanbuf[t] = acc; __syncthreads();
    }
    if (t < SNB) baseS[t] = acc - v;
    if (t == 0) baseS[SNB] = cnt;
  }
  __syncthreads();
  // cursors start at local bases
  for (int b = t; b < DNB; b += TPBS) curD[b] = baseD[b];
  for (int b = t; b < SNB; b += TPBS) curS[b] = baseS[b];
  __syncthreads();

  // LDS scatter: block-local bucket-sorted staging
#pragma unroll
  for (int j = 0; j < EPT; ++j) {
    if (ed[j] >= 0) {
      int p = atomicAdd(&curD[ed[j] >> DSH], 1);
      pack_lds[p] = (es[j] << DSH) | (ed[j] & (DCB - 1));
      int q = atomicAdd(&curS[es[j] >> SSH], 1);
      ss_lds[q] = (unsigned short)(es[j] & (SCB - 1));
    }
  }
  __syncthreads();

  // burst flush: element i -> bucket via binary search on baseD/baseS;
  // consecutive i within a bucket hit consecutive global addresses.
  for (int i = t; i < cnt; i += TPBS) {
    int lo = 0, hi = DNB;
    while (hi - lo > 1) { int mid = (lo + hi) >> 1; if (baseD[mid] <= i) lo = mid; else hi = mid; }
    packed[Hsc[lo * NBLK + k] + (i - baseD[lo])] = pack_lds[i];
  }
  for (int i = t; i < cnt; i += TPBS) {
    int lo = 0, hi = SNB;
    while (hi - lo > 1) { int mid = (lo + hi) >> 1; if (baseS[mid] <= i) lo = mid; else hi = mid; }
    ss[Hsc[HLD + lo * NBLK + k] + (i - baseS[lo]) - NE] = ss_lds[i];
  }
}

// ------ D: per-bucket fine counting sort (dst) -> src_sorted/row_ptr/norm_in
__global__ __launch_bounds__(TPB) void k_fine_sort(const int* __restrict__ Hsc,
                                                   const int* __restrict__ packed,
                                                   int* __restrict__ src_sorted,
                                                   int* __restrict__ row_ptr,
                                                   float* __restrict__ norm_in) {
  __shared__ int hist[DCB], scn[DCB], cur[DCB];
  __shared__ int pool[POOL];
  int t = threadIdx.x, b = blockIdx.x;
  int seg_beg = Hsc[b * NBLK];
  int seg_end = (b + 1 < DNB) ? Hsc[(b + 1) * NBLK] : NE;
  int cnt = seg_end - seg_beg;
  hist[t] = 0;
  __syncthreads();
  for (int i = seg_beg + t; i < seg_end; i += TPB)
    atomicAdd(&hist[packed[i] & (DCB - 1)], 1);
  __syncthreads();
  scn[t] = hist[t];
  __syncthreads();
  for (int off = 1; off < DCB; off <<= 1) {   // Hillis-Steele inclusive (256=TPB)
    int add = (t >= off) ? scn[t - off] : 0;
    __syncthreads();
    scn[t] += add;
    __syncthreads();
  }
  {
    int excl = scn[t] - hist[t];
    cur[t] = excl;
    int node = b * DCB + t;
    if (node < NN) {
      row_ptr[node] = seg_beg + excl;
      norm_in[node] = (hist[t] > 0) ? rsqrtf((float)hist[t]) : 0.0f;
    }
  }
  if (b == DNB - 1 && t == 0) row_ptr[NN] = NE;
  __syncthreads();
  for (int i = seg_beg + t; i < seg_end; i += TPB) {
    int v = packed[i];
    int p = atomicAdd(&cur[v & (DCB - 1)], 1);
    int sv = v >> DSH;
    if (p < POOL) pool[p] = sv;
    else src_sorted[seg_beg + p] = sv;                 // overflow fallback (rare)
  }
  __syncthreads();
  int lim = min(cnt, POOL);
  for (int i = t; i < lim; i += TPB) src_sorted[seg_beg + i] = pool[i];
}

// ------ E: per-bucket fine count (src, 1024 bins) -> norm_out ---------------
__global__ __launch_bounds__(TPB) void k_fine_count(const int* __restrict__ Hsc,
                                                    const unsigned short* __restrict__ ss,
                                                    float* __restrict__ norm_out) {
  __shared__ int hist[SCB];
  int t = threadIdx.x, b = blockIdx.x;
  int seg_beg = Hsc[HLD + b * NBLK] - NE;
  int seg_end = (b + 1 < SNB) ? Hsc[HLD + (b + 1) * NBLK] - NE : NE;
  for (int i = t; i < SCB; i += TPB) hist[i] = 0;
  __syncthreads();
  for (int i = seg_beg + t; i < seg_end; i += TPB)
    atomicAdd(&hist[ss[i]], 1);
  __syncthreads();
  for (int i = t; i < SCB; i += TPB) {
    int node = b * SCB + i;
    if (node < NN)
      norm_out[node] = (hist[i] > 0) ? rsqrtf((float)hist[i]) : 0.0f;
  }
}

// ------ GEMM1: xt_b[n] = bf16( norm_out[n] * (x[n] @ W1) )  [64 -> 64] ------
__global__ __launch_bounds__(TPB) void k_gemm1(const float4* __restrict__ x4,
                                               const float* __restrict__ W1,
                                               const float* __restrict__ norm_out,
                                               unsigned short* __restrict__ xt_b) {
  int lane = threadIdx.x & 63;
  int wid = (blockIdx.x * TPB + threadIdx.x) >> 6;
  int nwaves = gridDim.x * (TPB / 64);
  float w[64];
#pragma unroll
  for (int k = 0; k < 64; ++k) w[k] = W1[k * 64 + lane];
  int m = lane >> 4, q = lane & 15;
  for (int grp = wid; grp < NN / 4; grp += nwaves) {
    int nbase = grp * 4;
    float4 rv = x4[(nbase + m) * 16 + q];
    int r0 = __float_as_int(rv.x), r1 = __float_as_int(rv.y);
    int r2 = __float_as_int(rv.z), r3 = __float_as_int(rv.w);
    float acc[4] = {0.f, 0.f, 0.f, 0.f};
#pragma unroll
    for (int mm = 0; mm < 4; ++mm) {
#pragma unroll
      for (int ql = 0; ql < 16; ++ql) {
        int sl = mm * 16 + ql;
        acc[mm] = fmaf(__int_as_float(__builtin_amdgcn_readlane(r0, sl)), w[ql * 4 + 0], acc[mm]);
        acc[mm] = fmaf(__int_as_float(__builtin_amdgcn_readlane(r1, sl)), w[ql * 4 + 1], acc[mm]);
        acc[mm] = fmaf(__int_as_float(__builtin_amdgcn_readlane(r2, sl)), w[ql * 4 + 2], acc[mm]);
        acc[mm] = fmaf(__int_as_float(__builtin_amdgcn_readlane(r3, sl)), w[ql * 4 + 3], acc[mm]);
      }
    }
#pragma unroll
    for (int mm = 0; mm < 4; ++mm) {
      int n = nbase + mm;
      xt_b[n * 64 + lane] = f2bf(norm_out[n] * acc[mm]);  // 128B/row coalesced
    }
  }
}

// -- GEMM2: h1t_b[n][0:32] = bf16( norm_out[n]*(h1[n] @ W2) ), cols 30,31=0 --
__global__ __launch_bounds__(TPB) void k_gemm2(const float4* __restrict__ h1_4,
                                               const float* __restrict__ W2,
                                               const float* __restrict__ norm_out,
                                               unsigned short* __restrict__ h1t_b) {
  int lane = threadIdx.x & 63;
  int wid = (blockIdx.x * TPB + threadIdx.x) >> 6;
  int nwaves = gridDim.x * (TPB / 64);
  int gclamp = (lane < NOUTF) ? lane : 0;
  float w[64];
#pragma unroll
  for (int k = 0; k < 64; ++k) {
    float wv = W2[k * NOUTF + gclamp];
    w[k] = (lane < NOUTF) ? wv : 0.f;
  }
  int m = lane >> 4, q = lane & 15;
  for (int grp = wid; grp < NN / 4; grp += nwaves) {
    int nbase = grp * 4;
    float4 rv = h1_4[(nbase + m) * 16 + q];
    int r0 = __float_as_int(rv.x), r1 = __float_as_int(rv.y);
    int r2 = __float_as_int(rv.z), r3 = __float_as_int(rv.w);
    float acc[4] = {0.f, 0.f, 0.f, 0.f};
#pragma unroll
    for (int mm = 0; mm < 4; ++mm) {
#pragma unroll
      for (int ql = 0; ql < 16; ++ql) {
        int sl = mm * 16 + ql;
        acc[mm] = fmaf(__int_as_float(__builtin_amdgcn_readlane(r0, sl)), w[ql * 4 + 0], acc[mm]);
        acc[mm] = fmaf(__int_as_float(__builtin_amdgcn_readlane(r1, sl)), w[ql * 4 + 1], acc[mm]);
        acc[mm] = fmaf(__int_as_float(__builtin_amdgcn_readlane(r2, sl)), w[ql * 4 + 2], acc[mm]);
        acc[mm] = fmaf(__int_as_float(__builtin_amdgcn_readlane(r3, sl)), w[ql * 4 + 3], acc[mm]);
      }
    }
    if (lane < 32) {
#pragma unroll
      for (int mm = 0; mm < 4; ++mm) {
        int n = nbase + mm;
        unsigned short v = (lane < NOUTF) ? f2bf(norm_out[n] * acc[mm]) : (unsigned short)0;
        h1t_b[n * 32 + lane] = v;  // 64B/row
      }
    }
  }
}

// -- AGG1: h1[n] = relu(norm_in[n]*segsum(xt_b[src]) + b1); bf16 in, f32 out -
__global__ __launch_bounds__(TPB) void k_agg1(const uint4* __restrict__ xt4,
                                              const int* __restrict__ src_sorted,
                                              const int* __restrict__ row_ptr,
                                              const float* __restrict__ norm_in,
                                              const float* __restrict__ b1,
                                              float4* __restrict__ h1_4) {
  int node = (blockIdx.x * TPB + threadIdx.x) >> 6;
  int lane = threadIdx.x & 63;
  int slot = lane >> 3;  // 0..7
  int fl = lane & 7;     // uint4 index within 128B row
  int beg = row_ptr[node];
  int end = row_ptr[node + 1];
  float a[8] = {0.f, 0.f, 0.f, 0.f, 0.f, 0.f, 0.f, 0.f};
  int e = beg + slot;
  for (; e + 8 < end; e += 16) {
    int s0 = src_sorted[e];
    int s1 = src_sorted[e + 8];
    uint4 u0 = xt4[s0 * 8 + fl];
    uint4 u1 = xt4[s1 * 8 + fl];
    acc8(a, u0);
    acc8(a, u1);
  }
  if (e < end) {
    uint4 u0 = xt4[src_sorted[e] * 8 + fl];
    acc8(a, u0);
  }
#pragma unroll
  for (int off = 8; off <= 32; off <<= 1) {
#pragma unroll
    for (int j = 0; j < 8; ++j) a[j] += __shfl_xor(a[j], off);
  }
  if (slot == 0) {
    float ni = norm_in[node];
    float4 blo = reinterpret_cast<const float4*>(b1)[fl * 2];
    float4 bhi = reinterpret_cast<const float4*>(b1)[fl * 2 + 1];
    float4 r0, r1;
    r0.x = fmaxf(fmaf(a[0], ni, blo.x), 0.f);
    r0.y = fmaxf(fmaf(a[1], ni, blo.y), 0.f);
    r0.z = fmaxf(fmaf(a[2], ni, blo.z), 0.f);
    r0.w = fmaxf(fmaf(a[3], ni, blo.w), 0.f);
    r1.x = fmaxf(fmaf(a[4], ni, bhi.x), 0.f);
    r1.y = fmaxf(fmaf(a[5], ni, bhi.y), 0.f);
    r1.z = fmaxf(fmaf(a[6], ni, bhi.z), 0.f);
    r1.w = fmaxf(fmaf(a[7], ni, bhi.w), 0.f);
    h1_4[node * 16 + fl * 2] = r0;
    h1_4[node * 16 + fl * 2 + 1] = r1;
  }
}

// -- AGG2: out[n] = norm_in[n]*segsum(h1t_b[src]) + b2; bf16 in, f32 out -----
__global__ __launch_bounds__(TPB) void k_agg2(const uint4* __restrict__ h1t4,
                                              const int* __restrict__ src_sorted,
                                              const int* __restrict__ row_ptr,
                                              const float* __restrict__ norm_in,
                                              const float* __restrict__ b2,
                                              float* __restrict__ out) {
  int node = (blockIdx.x * TPB + threadIdx.x) >> 6;
  int lane = threadIdx.x & 63;
  int slot = lane >> 2;  // 0..15
  int fl = lane & 3;     // uint4 index within 64B row
  int beg = row_ptr[node];
  int end = row_ptr[node + 1];
  float a[8] = {0.f, 0.f, 0.f, 0.f, 0.f, 0.f, 0.f, 0.f};
  int e = beg + slot;
  for (; e + 16 < end; e += 32) {
    int s0 = src_sorted[e];
    int s1 = src_sorted[e + 16];
    uint4 u0 = h1t4[s0 * 4 + fl];
    uint4 u1 = h1t4[s1 * 4 + fl];
    acc8(a, u0);
    acc8(a, u1);
  }
  if (e < end) {
    uint4 u0 = h1t4[src_sorted[e] * 4 + fl];
    acc8(a, u0);
  }
#pragma unroll
  for (int off = 4; off <= 32; off <<= 1) {
#pragma unroll
    for (int j = 0; j < 8; ++j) a[j] += __shfl_xor(a[j], off);
  }
  if (slot == 0) {
    float ni = norm_in[node];
    int f0 = fl * 8;
    float2* ob = (float2*)(out + (size_t)node * NOUTF);  // rows 120B, 8B-aligned
#pragma unroll
    for (int p = 0; p < 4; ++p) {
      int f = f0 + p * 2;
      if (f < NOUTF) {
        float2 v;
        v.x = fmaf(a[p * 2], ni, b2[f]);
        v.y = fmaf(a[p * 2 + 1], ni, b2[f + 1]);
        ob[f >> 1] = v;
      }
    }
  }
}

extern "C" void kernel_launch(void* const* d_in, const int* in_sizes, int n_in,
                              void* d_out, int out_size, void* d_ws, size_t ws_size,
                              hipStream_t stream) {
  (void)in_sizes; (void)n_in; (void)out_size; (void)ws_size;
  const float* x = (const float*)d_in[0];
  const int* src = (const int*)d_in[1];
  const int* dst = (const int*)d_in[2];
  const float* W1 = (const float*)d_in[3];
  const float* b1 = (const float*)d_in[4];
  const float* W2 = (const float*)d_in[5];
  const float* b2 = (const float*)d_in[6];
  float* out = (float*)d_out;

  // Workspace layout (bytes), total 59,565,696; offsets 16B-aligned.
  // packed (12.8MB) dead after k_fine_sort -> h1 (25.6MB f32) aliases it.
  // xt_b (12.8MB bf16) dead after agg1 -> h1t_b (6.4MB) aliases it.
  char* ws = (char*)d_ws;
  int* row_ptr = (int*)(ws + 0);                           //    400,128
  float* norm_out = (float*)(ws + 400128);                 //    400,000
  float* norm_in = (float*)(ws + 800128);                  //    400,000
  int* H = (int*)(ws + 1200128);                           //    764,800 (HLT ints pad)
  int* bsums = (int*)(ws + 1964928);                       //        768 (NSC ints pad)
  unsigned short* ss = (unsigned short*)(ws + 1965696);    //  6,400,000
  int* src_sorted = (int*)(ws + 8365696);                  // 12,800,000
  int* packed = (int*)(ws + 21165696);                     // 12,800,000
  float* h1 = (float*)(ws + 21165696);                     // 25,600,000 (aliases packed)
  unsigned short* xt_b = (unsigned short*)(ws + 46765696); // 12,800,000
  unsigned short* h1t_b = xt_b;                            // reuse (6.4MB)

  k_hist<<<NBLK, TPBW, 0, stream>>>(src, dst, H);
  g_scan1<<<NSC, TPB, 0, stream>>>(H, bsums);
  g_scan2<<<1, 1024, 0, stream>>>(bsums);
  g_scan3<<<NSC, TPB, 0, stream>>>(H, bsums);
  k_scatter<<<NBLK, TPBS, 0, stream>>>(src, dst, H, packed, ss);
  k_fine_sort<<<DNB, TPB, 0, stream>>>(H, packed, src_sorted, row_ptr, norm_in);
  k_fine_count<<<SNB, TPB, 0, stream>>>(H, ss, norm_out);
  k_gemm1<<<1024, TPB, 0, stream>>>((const float4*)x, W1, norm_out, xt_b);
  k_agg1<<<NN / 4, TPB, 0, stream>>>((const uint4*)xt_b, src_sorted, row_ptr, norm_in, b1, (float4*)h1);
  k_gemm2<<<1024, TPB, 0, stream>>>((const float4*)h1, W2, norm_out, h1t_b);
  k_agg2<<<NN / 4, TPB, 0, stream>>>((const uint4*)h1t_b, src_sorted, row_ptr, norm_in, b2, out);
}

// Round 8
// 260.379 us; speedup vs baseline: 1.2828x; 1.1143x over previous
//
#include <hip/hip_runtime.h>

// GCN 2-layer, round 8: 4-deep gather MLP + GEMM2 fused into AGG1 epilogue.
// r7 profile: k_agg1 57.7us top (FETCH 156MB, VALUBusy 50%, occ 73%) --
// mixed latency/VALU regime; h1 f32 round-trip (51MB) feeds k_gemm2.
// Changes: (1) agg1 gathers 4 independent uint4 loads/iter (clamped+masked,
// covers deg<=32 in one iteration); (2) slot0 writes h1 row to LDS, block
// epilogue computes h1@W2 (W2 LDS-staged) and writes h1t_b bf16 directly;
// k_gemm2 deleted. h1t_b relocated to the dead `packed` region (cannot alias
// xt_b which agg1 still reads).
// CSR build unchanged from r7 (LDS-staged burst-flush scatter, no global
// atomics). Transform-first identity: segsum(h[src]) @ W == segsum((h@W)[src]).

#define NN 100000
#define NE 3200000
#define NOUTF 30
#define TPB 256
#define TPBW 1024                          // hist blocks
#define TPBS 512                           // scatter blocks

// dst stream buckets
#define DSH 8
#define DCB 256
#define DNB ((NN + DCB - 1) / DCB)         // 391
// src stream buckets
#define SSH 10
#define SCB 1024
#define SNB ((NN + SCB - 1) / SCB)         // 98

#define CHUNK 8192
#define NBLK ((NE + CHUNK - 1) / CHUNK)    // 391
#define HLD (DNB * NBLK)                   // 152,881
#define HLS (SNB * NBLK)                   // 38,318
#define HLT (HLD + HLS)                    // 191,199
#define EPT (CHUNK / TPBS)                 // 16 edges per scatter thread

#define GCH 1024
#define NSC ((HLT + GCH - 1) / GCH)        // 187

#define POOL 9216                          // fine-sort staging (36KB LDS)

__device__ __forceinline__ unsigned short f2bf(float f) {  // round-nearest-even
  unsigned u = __float_as_uint(f);
  u = (u + 0x7FFFu + ((u >> 16) & 1u)) >> 16;
  return (unsigned short)u;
}

// accumulate 8 bf16 (one uint4) into 8 f32
__device__ __forceinline__ void acc8(float* a, const uint4& u) {
  a[0] += __uint_as_float(u.x << 16);
  a[1] += __uint_as_float(u.x & 0xFFFF0000u);
  a[2] += __uint_as_float(u.y << 16);
  a[3] += __uint_as_float(u.y & 0xFFFF0000u);
  a[4] += __uint_as_float(u.z << 16);
  a[5] += __uint_as_float(u.z & 0xFFFF0000u);
  a[6] += __uint_as_float(u.w << 16);
  a[7] += __uint_as_float(u.w & 0xFFFF0000u);
}

__device__ __forceinline__ uint4 sel4(bool ok, uint4 u) {  // -> v_cndmask x4
  uint4 z = make_uint4(0u, 0u, 0u, 0u);
  return ok ? u : z;
}

// bijective XCD swizzle (m204 variant): consecutive swizzled ids -> same XCD
__device__ __forceinline__ int xcd_swz(int orig, int n) {
  int q = n / 8, r = n % 8;
  int xcd = orig % 8, idx = orig / 8;
  return (xcd < r ? xcd * (q + 1) : r * (q + 1) + (xcd - r) * q) + idx;
}

// ------ A: dual coarse histogram (dst>>8 and src>>10, LDS only) -------------
__global__ __launch_bounds__(TPBW) void k_hist(const int* __restrict__ src,
                                               const int* __restrict__ dst,
                                               int* __restrict__ H) {
  __shared__ int hd[DNB], hs[SNB];
  int t = threadIdx.x, k = blockIdx.x;
  for (int b = t; b < DNB; b += TPBW) hd[b] = 0;
  for (int b = t; b < SNB; b += TPBW) hs[b] = 0;
  __syncthreads();
  int beg = k * CHUNK, end = min(NE, beg + CHUNK);
  for (int i = beg + t; i < end; i += TPBW) {
    atomicAdd(&hd[dst[i] >> DSH], 1);
    atomicAdd(&hs[src[i] >> SSH], 1);
  }
  __syncthreads();
  for (int b = t; b < DNB; b += TPBW) H[b * NBLK + k] = hd[b];
  for (int b = t; b < SNB; b += TPBW) H[HLD + b * NBLK + k] = hs[b];
}

// ------ B: 3-kernel exclusive scan over H[HLT] -------------------------------
__global__ __launch_bounds__(TPB) void g_scan1(const int* __restrict__ a,
                                               int* __restrict__ bsums) {
  int t = threadIdx.x;
  int base = blockIdx.x * GCH + t * 4;
  int s = 0;
#pragma unroll
  for (int j = 0; j < 4; ++j) { int idx = base + j; if (idx < HLT) s += a[idx]; }
  __shared__ int red[TPB];
  red[t] = s; __syncthreads();
  for (int off = TPB / 2; off > 0; off >>= 1) {
    if (t < off) red[t] += red[t + off];
    __syncthreads();
  }
  if (t == 0) bsums[blockIdx.x] = red[0];
}

__global__ __launch_bounds__(1024) void g_scan2(int* __restrict__ bsums) {
  int t = threadIdx.x;
  __shared__ int lds[1024];
  int v = (t < NSC) ? bsums[t] : 0;
  int acc = v; lds[t] = acc; __syncthreads();
  for (int off = 1; off < 1024; off <<= 1) {
    int add = (t >= off) ? lds[t - off] : 0; __syncthreads();
    acc += add; lds[t] = acc; __syncthreads();
  }
  if (t < NSC) bsums[t] = acc - v;  // exclusive
}

__global__ __launch_bounds__(TPB) void g_scan3(int* __restrict__ a,
                                               const int* __restrict__ bsums) {
  int t = threadIdx.x;
  int base = blockIdx.x * GCH + t * 4;
  int v[4]; int s = 0;
#pragma unroll
  for (int j = 0; j < 4; ++j) {
    int idx = base + j;
    v[j] = (idx < HLT) ? a[idx] : 0;
    s += v[j];
  }
  __shared__ int lds[TPB];
  int acc = s; lds[t] = acc; __syncthreads();
  for (int off = 1; off < TPB; off <<= 1) {
    int add = (t >= off) ? lds[t - off] : 0; __syncthreads();
    acc += add; lds[t] = acc; __syncthreads();
  }
  int run = bsums[blockIdx.x] + (acc - s);
#pragma unroll
  for (int j = 0; j < 4; ++j) {
    int idx = base + j;
    if (idx < HLT) a[idx] = run;  // in-place exclusive
    run += v[j];
  }
}

// ------ C: LDS-staged dual scatter with contiguous burst flush --------------
__global__ __launch_bounds__(TPBS) void k_scatter(const int* __restrict__ src,
                                                  const int* __restrict__ dst,
                                                  const int* __restrict__ Hsc,
                                                  int* __restrict__ packed,
                                                  unsigned short* __restrict__ ss) {
  __shared__ int pack_lds[CHUNK];            // 32KB
  __shared__ unsigned short ss_lds[CHUNK];   // 16KB
  __shared__ int baseD[DNB + 1], curD[DNB];
  __shared__ int baseS[SNB + 1], curS[SNB];
  __shared__ int scanbuf[TPBS];
  int t = threadIdx.x;
  int k = xcd_swz((int)blockIdx.x, NBLK);    // adjacent chunks -> same XCD
  int beg = k * CHUNK, end = min(NE, beg + CHUNK);
  int cnt = end - beg;

  // register-stage this chunk's edges (coalesced reads, read once)
  int es[EPT], ed[EPT];
#pragma unroll
  for (int j = 0; j < EPT; ++j) {
    int i = beg + j * TPBS + t;
    if (i < end) { es[j] = src[i]; ed[j] = dst[i]; }
    else { es[j] = -1; ed[j] = -1; }
  }

  // block-local histograms (curD/curS double as hist accumulators)
  for (int b = t; b < DNB; b += TPBS) curD[b] = 0;
  for (int b = t; b < SNB; b += TPBS) curS[b] = 0;
  __syncthreads();
#pragma unroll
  for (int j = 0; j < EPT; ++j) {
    if (ed[j] >= 0) {
      atomicAdd(&curD[ed[j] >> DSH], 1);
      atomicAdd(&curS[es[j] >> SSH], 1);
    }
  }
  __syncthreads();

  // exclusive scan of curD -> baseD (DNB=391 <= TPBS)
  {
    int v = (t < DNB) ? curD[t] : 0;
    int acc = v; scanbuf[t] = acc; __syncthreads();
    for (int off = 1; off < TPBS; off <<= 1) {
      int add = (t >= off) ? scanbuf[t - off] : 0; __syncthreads();
      acc += add; scanbuf[t] = acc; __syncthreads();
    }
    if (t < DNB) baseD[t] = acc - v;
    if (t == 0) baseD[DNB] = cnt;
  }
  __syncthreads();
  // exclusive scan of curS -> baseS (SNB=98)
  {
    int v = (t < SNB) ? curS[t] : 0;
    int acc = v; scanbuf[t] = acc; __syncthreads();
    for (int off = 1; off < TPBS; off <<= 1) {
      int add = (t >= off) ? scanbuf[t - off] : 0; __syncthreads();
      acc += add; scanbuf[t] = acc; __syncthreads();
    }
    if (t < SNB) baseS[t] = acc - v;
    if (t == 0) baseS[SNB] = cnt;
  }
  __syncthreads();
  // cursors start at local bases
  for (int b = t; b < DNB; b += TPBS) curD[b] = baseD[b];
  for (int b = t; b < SNB; b += TPBS) curS[b] = baseS[b];
  __syncthreads();

  // LDS scatter: block-local bucket-sorted staging
#pragma unroll
  for (int j = 0; j < EPT; ++j) {
    if (ed[j] >= 0) {
      int p = atomicAdd(&curD[ed[j] >> DSH], 1);
      pack_lds[p] = (es[j] << DSH) | (ed[j] & (DCB - 1));
      int q = atomicAdd(&curS[es[j] >> SSH], 1);
      ss_lds[q] = (unsigned short)(es[j] & (SCB - 1));
    }
  }
  __syncthreads();

  // burst flush: element i -> bucket via binary search on baseD/baseS;
  // consecutive i within a bucket hit consecutive global addresses.
  for (int i = t; i < cnt; i += TPBS) {
    int lo = 0, hi = DNB;
    while (hi - lo > 1) { int mid = (lo + hi) >> 1; if (baseD[mid] <= i) lo = mid; else hi = mid; }
    packed[Hsc[lo * NBLK + k] + (i - baseD[lo])] = pack_lds[i];
  }
  for (int i = t; i < cnt; i += TPBS) {
    int lo = 0, hi = SNB;
    while (hi - lo > 1) { int mid = (lo + hi) >> 1; if (baseS[mid] <= i) lo = mid; else hi = mid; }
    ss[Hsc[HLD + lo * NBLK + k] + (i - baseS[lo]) - NE] = ss_lds[i];
  }
}

// ------ D: per-bucket fine counting sort (dst) -> src_sorted/row_ptr/norm_in
__global__ __launch_bounds__(TPB) void k_fine_sort(const int* __restrict__ Hsc,
                                                   const int* __restrict__ packed,
                                                   int* __restrict__ src_sorted,
                                                   int* __restrict__ row_ptr,
                                                   float* __restrict__ norm_in) {
  __shared__ int hist[DCB], scn[DCB], cur[DCB];
  __shared__ int pool[POOL];
  int t = threadIdx.x, b = blockIdx.x;
  int seg_beg = Hsc[b * NBLK];
  int seg_end = (b + 1 < DNB) ? Hsc[(b + 1) * NBLK] : NE;
  int cnt = seg_end - seg_beg;
  hist[t] = 0;
  __syncthreads();
  for (int i = seg_beg + t; i < seg_end; i += TPB)
    atomicAdd(&hist[packed[i] & (DCB - 1)], 1);
  __syncthreads();
  scn[t] = hist[t];
  __syncthreads();
  for (int off = 1; off < DCB; off <<= 1) {   // Hillis-Steele inclusive (256=TPB)
    int add = (t >= off) ? scn[t - off] : 0;
    __syncthreads();
    scn[t] += add;
    __syncthreads();
  }
  {
    int excl = scn[t] - hist[t];
    cur[t] = excl;
    int node = b * DCB + t;
    if (node < NN) {
      row_ptr[node] = seg_beg + excl;
      norm_in[node] = (hist[t] > 0) ? rsqrtf((float)hist[t]) : 0.0f;
    }
  }
  if (b == DNB - 1 && t == 0) row_ptr[NN] = NE;
  __syncthreads();
  for (int i = seg_beg + t; i < seg_end; i += TPB) {
    int v = packed[i];
    int p = atomicAdd(&cur[v & (DCB - 1)], 1);
    int sv = v >> DSH;
    if (p < POOL) pool[p] = sv;
    else src_sorted[seg_beg + p] = sv;                 // overflow fallback (rare)
  }
  __syncthreads();
  int lim = min(cnt, POOL);
  for (int i = t; i < lim; i += TPB) src_sorted[seg_beg + i] = pool[i];
}

// ------ E: per-bucket fine count (src, 1024 bins) -> norm_out ---------------
__global__ __launch_bounds__(TPB) void k_fine_count(const int* __restrict__ Hsc,
                                                    const unsigned short* __restrict__ ss,
                                                    float* __restrict__ norm_out) {
  __shared__ int hist[SCB];
  int t = threadIdx.x, b = blockIdx.x;
  int seg_beg = Hsc[HLD + b * NBLK] - NE;
  int seg_end = (b + 1 < SNB) ? Hsc[HLD + (b + 1) * NBLK] - NE : NE;
  for (int i = t; i < SCB; i += TPB) hist[i] = 0;
  __syncthreads();
  for (int i = seg_beg + t; i < seg_end; i += TPB)
    atomicAdd(&hist[ss[i]], 1);
  __syncthreads();
  for (int i = t; i < SCB; i += TPB) {
    int node = b * SCB + i;
    if (node < NN)
      norm_out[node] = (hist[i] > 0) ? rsqrtf((float)hist[i]) : 0.0f;
  }
}

// ------ GEMM1: xt_b[n] = bf16( norm_out[n] * (x[n] @ W1) )  [64 -> 64] ------
__global__ __launch_bounds__(TPB) void k_gemm1(const float4* __restrict__ x4,
                                               const float* __restrict__ W1,
                                               const float* __restrict__ norm_out,
                                               unsigned short* __restrict__ xt_b) {
  int lane = threadIdx.x & 63;
  int wid = (blockIdx.x * TPB + threadIdx.x) >> 6;
  int nwaves = gridDim.x * (TPB / 64);
  float w[64];
#pragma unroll
  for (int k = 0; k < 64; ++k) w[k] = W1[k * 64 + lane];
  int m = lane >> 4, q = lane & 15;
  for (int grp = wid; grp < NN / 4; grp += nwaves) {
    int nbase = grp * 4;
    float4 rv = x4[(nbase + m) * 16 + q];
    int r0 = __float_as_int(rv.x), r1 = __float_as_int(rv.y);
    int r2 = __float_as_int(rv.z), r3 = __float_as_int(rv.w);
    float acc[4] = {0.f, 0.f, 0.f, 0.f};
#pragma unroll
    for (int mm = 0; mm < 4; ++mm) {
#pragma unroll
      for (int ql = 0; ql < 16; ++ql) {
        int sl = mm * 16 + ql;
        acc[mm] = fmaf(__int_as_float(__builtin_amdgcn_readlane(r0, sl)), w[ql * 4 + 0], acc[mm]);
        acc[mm] = fmaf(__int_as_float(__builtin_amdgcn_readlane(r1, sl)), w[ql * 4 + 1], acc[mm]);
        acc[mm] = fmaf(__int_as_float(__builtin_amdgcn_readlane(r2, sl)), w[ql * 4 + 2], acc[mm]);
        acc[mm] = fmaf(__int_as_float(__builtin_amdgcn_readlane(r3, sl)), w[ql * 4 + 3], acc[mm]);
      }
    }
#pragma unroll
    for (int mm = 0; mm < 4; ++mm) {
      int n = nbase + mm;
      xt_b[n * 64 + lane] = f2bf(norm_out[n] * acc[mm]);  // 128B/row coalesced
    }
  }
}

// -- AGG1+GEMM2 fused: per node, h1 = relu(norm_in*segsum(xt_b[src]) + b1);
// then h1t_b[n][0:32] = bf16(norm_out[n] * (h1 @ W2)) via LDS epilogue. ------
__global__ __launch_bounds__(TPB) void k_agg1f(const uint4* __restrict__ xt4,
                                               const int* __restrict__ src_sorted,
                                               const int* __restrict__ row_ptr,
                                               const float* __restrict__ norm_in,
                                               const float* __restrict__ norm_out,
                                               const float* __restrict__ b1,
                                               const float* __restrict__ W2,
                                               unsigned short* __restrict__ h1t_b) {
  __shared__ __align__(16) float h1s[4][64];   // 4 nodes/block (1 per wave)
  __shared__ float W2s[64][32];                // W2 staged, bank oc
  int t = threadIdx.x;
  for (int i = t; i < 64 * NOUTF; i += TPB)
    W2s[i / NOUTF][i % NOUTF] = W2[i];

  int w = t >> 6;               // wave id = node slot within block
  int lane = t & 63;
  int node = blockIdx.x * 4 + w;
  int slot = lane >> 3;         // 0..7 edge slots
  int fl = lane & 7;            // uint4 index within 128B row
  int beg = row_ptr[node];
  int end = row_ptr[node + 1];
  float a[8] = {0.f, 0.f, 0.f, 0.f, 0.f, 0.f, 0.f, 0.f};
  if (beg < end) {
    int last = end - 1;
    for (int e = beg + slot; e < end; e += 32) {   // 4 edges/lane-iter, 4 loads in flight
      int e1 = min(e + 8, last), e2 = min(e + 16, last), e3 = min(e + 24, last);
      bool k1 = (e + 8) < end, k2 = (e + 16) < end, k3 = (e + 24) < end;
      int s0 = src_sorted[e], s1 = src_sorted[e1];
      int s2 = src_sorted[e2], s3 = src_sorted[e3];
      uint4 u0 = xt4[s0 * 8 + fl];
      uint4 u1 = xt4[s1 * 8 + fl];
      uint4 u2 = xt4[s2 * 8 + fl];
      uint4 u3 = xt4[s3 * 8 + fl];
      u1 = sel4(k1, u1); u2 = sel4(k2, u2); u3 = sel4(k3, u3);
      acc8(a, u0); acc8(a, u1); acc8(a, u2); acc8(a, u3);
    }
  }
#pragma unroll
  for (int off = 8; off <= 32; off <<= 1) {
#pragma unroll
    for (int j = 0; j < 8; ++j) a[j] += __shfl_xor(a[j], off);
  }
  if (slot == 0) {
    float ni = norm_in[node];
    float4 blo = reinterpret_cast<const float4*>(b1)[fl * 2];
    float4 bhi = reinterpret_cast<const float4*>(b1)[fl * 2 + 1];
    float4 r0, r1;
    r0.x = fmaxf(fmaf(a[0], ni, blo.x), 0.f);
    r0.y = fmaxf(fmaf(a[1], ni, blo.y), 0.f);
    r0.z = fmaxf(fmaf(a[2], ni, blo.z), 0.f);
    r0.w = fmaxf(fmaf(a[3], ni, blo.w), 0.f);
    r1.x = fmaxf(fmaf(a[4], ni, bhi.x), 0.f);
    r1.y = fmaxf(fmaf(a[5], ni, bhi.y), 0.f);
    r1.z = fmaxf(fmaf(a[6], ni, bhi.z), 0.f);
    r1.w = fmaxf(fmaf(a[7], ni, bhi.w), 0.f);
    *reinterpret_cast<float4*>(&h1s[w][fl * 8]) = r0;
    *reinterpret_cast<float4*>(&h1s[w][fl * 8 + 4]) = r1;
  }
  __syncthreads();
  if (t < 128) {                 // 4 nodes x 32 padded outputs
    int wn = t >> 5, oc = t & 31;
    int n = blockIdx.x * 4 + wn;
    if (oc < NOUTF) {
      float a0 = 0.f, a1 = 0.f, a2 = 0.f, a3 = 0.f;
#pragma unroll
      for (int k = 0; k < 64; k += 4) {
        a0 = fmaf(h1s[wn][k],     W2s[k][oc],     a0);
        a1 = fmaf(h1s[wn][k + 1], W2s[k + 1][oc], a1);
        a2 = fmaf(h1s[wn][k + 2], W2s[k + 2][oc], a2);
        a3 = fmaf(h1s[wn][k + 3], W2s[k + 3][oc], a3);
      }
      h1t_b[n * 32 + oc] = f2bf(norm_out[n] * ((a0 + a1) + (a2 + a3)));
    } else {
      h1t_b[n * 32 + oc] = 0;    // pad cols 30,31
    }
  }
}

// -- AGG2: out[n] = norm_in[n]*segsum(h1t_b[src]) + b2; bf16 in, f32 out -----
__global__ __launch_bounds__(TPB) void k_agg2(const uint4* __restrict__ h1t4,
                                              const int* __restrict__ src_sorted,
                                              const int* __restrict__ row_ptr,
                                              const float* __restrict__ norm_in,
                                              const float* __restrict__ b2,
                                              float* __restrict__ out) {
  int node = (blockIdx.x * TPB + threadIdx.x) >> 6;
  int lane = threadIdx.x & 63;
  int slot = lane >> 2;  // 0..15
  int fl = lane & 3;     // uint4 index within 64B row
  int beg = row_ptr[node];
  int end = row_ptr[node + 1];
  float a[8] = {0.f, 0.f, 0.f, 0.f, 0.f, 0.f, 0.f, 0.f};
  int e = beg + slot;
  for (; e + 16 < end; e += 32) {
    int s0 = src_sorted[e];
    int s1 = src_sorted[e + 16];
    uint4 u0 = h1t4[s0 * 4 + fl];
    uint4 u1 = h1t4[s1 * 4 + fl];
    acc8(a, u0);
    acc8(a, u1);
  }
  if (e < end) {
    uint4 u0 = h1t4[src_sorted[e] * 4 + fl];
    acc8(a, u0);
  }
#pragma unroll
  for (int off = 4; off <= 32; off <<= 1) {
#pragma unroll
    for (int j = 0; j < 8; ++j) a[j] += __shfl_xor(a[j], off);
  }
  if (slot == 0) {
    float ni = norm_in[node];
    int f0 = fl * 8;
    float2* ob = (float2*)(out + (size_t)node * NOUTF);  // rows 120B, 8B-aligned
#pragma unroll
    for (int p = 0; p < 4; ++p) {
      int f = f0 + p * 2;
      if (f < NOUTF) {
        float2 v;
        v.x = fmaf(a[p * 2], ni, b2[f]);
        v.y = fmaf(a[p * 2 + 1], ni, b2[f + 1]);
        ob[f >> 1] = v;
      }
    }
  }
}

extern "C" void kernel_launch(void* const* d_in, const int* in_sizes, int n_in,
                              void* d_out, int out_size, void* d_ws, size_t ws_size,
                              hipStream_t stream) {
  (void)in_sizes; (void)n_in; (void)out_size; (void)ws_size;
  const float* x = (const float*)d_in[0];
  const int* src = (const int*)d_in[1];
  const int* dst = (const int*)d_in[2];
  const float* W1 = (const float*)d_in[3];
  const float* b1 = (const float*)d_in[4];
  const float* W2 = (const float*)d_in[5];
  const float* b2 = (const float*)d_in[6];
  float* out = (float*)d_out;

  // Workspace layout (bytes); offsets 16B-aligned.
  // packed (12.8MB) dead after k_fine_sort -> h1t_b (6.4MB bf16) aliases it
  // (h1t_b must NOT alias xt_b: k_agg1f reads xt_b while writing h1t_b).
  char* ws = (char*)d_ws;
  int* row_ptr = (int*)(ws + 0);                           //    400,128
  float* norm_out = (float*)(ws + 400128);                 //    400,000
  float* norm_in = (float*)(ws + 800128);                  //    400,000
  int* H = (int*)(ws + 1200128);                           //    764,800 (HLT ints pad)
  int* bsums = (int*)(ws + 1964928);                       //        768 (NSC ints pad)
  unsigned short* ss = (unsigned short*)(ws + 1965696);    //  6,400,000
  int* src_sorted = (int*)(ws + 8365696);                  // 12,800,000
  int* packed = (int*)(ws + 21165696);                     // 12,800,000
  unsigned short* h1t_b = (unsigned short*)(ws + 21165696);// 6,400,000 (aliases packed)
  unsigned short* xt_b = (unsigned short*)(ws + 46765696); // 12,800,000

  k_hist<<<NBLK, TPBW, 0, stream>>>(src, dst, H);
  g_scan1<<<NSC, TPB, 0, stream>>>(H, bsums);
  g_scan2<<<1, 1024, 0, stream>>>(bsums);
  g_scan3<<<NSC, TPB, 0, stream>>>(H, bsums);
  k_scatter<<<NBLK, TPBS, 0, stream>>>(src, dst, H, packed, ss);
  k_fine_sort<<<DNB, TPB, 0, stream>>>(H, packed, src_sorted, row_ptr, norm_in);
  k_fine_count<<<SNB, TPB, 0, stream>>>(H, ss, norm_out);
  k_gemm1<<<1024, TPB, 0, stream>>>((const float4*)x, W1, norm_out, xt_b);
  k_agg1f<<<NN / 4, TPB, 0, stream>>>((const uint4*)xt_b, src_sorted, row_ptr,
                                      norm_in, norm_out, b1, W2, h1t_b);
  k_agg2<<<NN / 4, TPB, 0, stream>>>((const uint4*)h1t_b, src_sorted, row_ptr, norm_in, b2, out);
}